// Round 4
// baseline (1688.848 us; speedup 1.0000x reference)
//
#include <hip/hip_runtime.h>
#include <stdint.h>

#define GLOBAL_AS __attribute__((address_space(1)))
#define LDS_AS    __attribute__((address_space(3)))

typedef __attribute__((ext_vector_type(8))) short  short8;   // 8 bf16 = 4 VGPRs
typedef __attribute__((ext_vector_type(4))) float  floatx4;

static constexpr int B_   = 4096;
static constexpr int T_   = 28;
static constexpr int IN_  = 28;
static constexpr int H_   = 1024;
static constexpr int G4_  = 4096;   // 4*H
static constexpr int OUT_ = 10;
static constexpr int NT_  = 16;     // K-tiles of 64 over H=1024

// ---------- small helpers ----------
__device__ __forceinline__ float bf2f(unsigned short u) {
  union { uint32_t i; float f; } v; v.i = ((uint32_t)u) << 16; return v.f;
}
__device__ __forceinline__ unsigned short f2bf(float f) {  // RTNE
  union { float f; uint32_t i; } v; v.f = f;
  uint32_t x = v.i;
  uint32_t lsb = (x >> 16) & 1u;
  x += 0x7fffu + lsb;
  return (unsigned short)(x >> 16);
}
__device__ __forceinline__ float sigm(float x) {
  return __builtin_amdgcn_rcpf(1.f + __builtin_amdgcn_exp2f(-1.4426950408889634f * x));
}
__device__ __forceinline__ float tanh_f(float x) {
  return 1.f - 2.f * __builtin_amdgcn_rcpf(1.f + __builtin_amdgcn_exp2f(2.8853900817779268f * x));
}
__device__ __forceinline__ void stage16(const unsigned short* g, unsigned short* l) {
  __builtin_amdgcn_global_load_lds(
      (const GLOBAL_AS uint32_t*)g, (LDS_AS uint32_t*)l, 16, 0, 0);
}

// ---------- prologue: x -> bf16 [T][B][32] (k padded 28->32 with zeros) ----------
__global__ __launch_bounds__(256) void conv_x_kernel(const float* __restrict__ x,
                                                     unsigned short* __restrict__ xb) {
  int row = blockIdx.x * 256 + threadIdx.x;   // row = t*4096 + b
  int t  = row >> 12;
  int bb = row & 4095;
  const float* src = x + (bb * T_ + t) * IN_;
  unsigned short* dst = xb + row * 32;
#pragma unroll
  for (int k = 0; k < IN_; ++k) dst[k] = f2bf(src[k]);
  dst[28] = 0; dst[29] = 0; dst[30] = 0; dst[31] = 0;
}

// ---------- prologue: W_hh [1024][4096] fp32 -> Wp [4096][1024] bf16, transposed+interleaved ----------
// permuted n = g64*64 + gate*16 + hw  <->  orig col = gate*1024 + g64*16 + hw
__global__ __launch_bounds__(256) void perm_whh_kernel(const float* __restrict__ whh,
                                                       unsigned short* __restrict__ wp) {
  __shared__ float lds[64][17];
  int g64  = blockIdx.x >> 2;
  int gate = blockIdx.x & 3;
  int oc0  = gate * H_ + g64 * 16;
  int n0   = g64 * 64 + gate * 16;
  int tid  = threadIdx.x;
  for (int kc = 0; kc < 16; ++kc) {
    int k0 = kc * 64;
    __syncthreads();
#pragma unroll
    for (int e = 0; e < 4; ++e) {
      int idx = e * 256 + tid;
      int k = idx >> 4, cc = idx & 15;
      lds[k][cc] = whh[(k0 + k) * G4_ + oc0 + cc];
    }
    __syncthreads();
#pragma unroll
    for (int e = 0; e < 4; ++e) {
      int idx = e * 256 + tid;
      int n = idx >> 6, kk = idx & 63;
      wp[(n0 + n) * H_ + k0 + kk] = f2bf(lds[kk][n]);
    }
  }
}

// ---------- prologue: W_ih [28][4096] -> Wip [4096][32] bf16 transposed+interleaved ----------
__global__ __launch_bounds__(256) void perm_wih_kernel(const float* __restrict__ wih,
                                                       unsigned short* __restrict__ wip) {
  __shared__ float lds[28][17];
  int g64  = blockIdx.x >> 2;
  int gate = blockIdx.x & 3;
  int oc0  = gate * H_ + g64 * 16;
  int n0   = g64 * 64 + gate * 16;
  int tid  = threadIdx.x;
  for (int idx = tid; idx < 448; idx += 256) {
    int k = idx >> 4, cc = idx & 15;
    lds[k][cc] = wih[k * G4_ + oc0 + cc];
  }
  __syncthreads();
#pragma unroll
  for (int e = 0; e < 2; ++e) {
    int idx = e * 256 + tid;
    int n = idx >> 5, kk = idx & 31;
    wip[(n0 + n) * 32 + kk] = (kk < IN_) ? f2bf(lds[kk][n]) : (unsigned short)0;
  }
}

// ================== LSTM step: 256x256 tile, 8-phase / 2-K-tile pipelined schedule ==================
// 8 waves (2M x 4N), per-wave 128x64, BK=64. ds_reads feed the NEXT phase's MFMA (one-phase-ahead
// register pipeline); staging 2 chunks/phase for tile t+2 into regions read 2 phases prior;
// vmcnt(8) counted wait per phase (never 0 in loop); no lgkmcnt asm in loop (compiler counts).
__global__ __launch_bounds__(512, 2) void lstm_step_kernel(
    const unsigned short* __restrict__ hprev,   // [B][H] bf16
    const unsigned short* __restrict__ wp,      // [4096][1024] bf16 (permuted^T)
    const unsigned short* __restrict__ xbt,     // [B][32] bf16 (this t)
    const unsigned short* __restrict__ wip,     // [4096][32] bf16 (permuted^T)
    const float* __restrict__ bias,             // [4096] original gate order
    float* __restrict__ cst,                    // [B][H] fp32
    unsigned short* __restrict__ hnext,         // [B][H] bf16
    int first) {
  __shared__ __align__(16) unsigned short lds[65536];   // 128 KiB: 2 x (A 32KB | B 32KB)

  const int tid = threadIdx.x;           // 0..511
  const int w   = tid >> 6;              // wave 0..7
  const int l   = tid & 63;
  const int wm  = w >> 2;                // 0..1  (M half)
  const int wn  = w & 3;                 // 0..3  (N quarter)
  const int lc  = l & 15;
  const int lk  = l >> 4;                // 0..3

  // XCD-aware bijective block swizzle (256 = 8*32)
  const int hid = blockIdx.x;
  const int lid = (hid & 7) * 32 + (hid >> 3);
  const int bx  = lid & 15, by = lid >> 4;
  const int m0  = bx * 256;              // batch rows
  const int n0  = by * 256;              // permuted gate cols

  const int swz  = (lc & 7) << 4;        // ds_read byte swizzle (main, 128B rows)
  const int swzx = (lc & 3) << 4;        // x-tile (64B rows)

  // ---- staging per-thread constants ----
  const int r8  = tid >> 3;              // main chunk-local row 0..63
  const int c8  = (tid & 7) * 8;         // ushort col within 64
  const int c8s = c8 ^ ((r8 & 7) * 8);   // pre-swizzled source col
  const size_t aoff = (size_t)(m0 + r8) * H_ + c8s;
  const int bwn_low = r8 >> 5;
  const int bc31    = r8 & 31;
  const int rx   = tid >> 2;             // x chunk-local row 0..127
  const int cx8  = (tid & 3) * 8;
  const int cx8s = cx8 ^ ((rx & 3) * 8);

  auto stageA = [&](int bufu, int kt, int i) {
    stage16(hprev + aoff + (size_t)i * (64 * H_) + kt * 64,
            lds + bufu + i * 4096 + tid * 8);
  };
  auto stageB = [&](int bufu, int kt, int j) {
    int col = n0 + (((j & 1) * 2 + bwn_low) * 64) + ((j >> 1) * 32) + bc31;
    stage16(wp + (size_t)col * H_ + c8s + kt * 64,
            lds + bufu + 16384 + j * 4096 + tid * 8);
  };
  auto stageXA = [&](int half) {
    int row = half * 128 + rx;
    stage16(xbt + (size_t)(m0 + row) * 32 + cx8s,
            lds + 32768 + half * 4096 + tid * 8);
  };
  auto stageXB = [&](int half) {
    int col = n0 + (rx >> 5) * 64 + half * 32 + (rx & 31);
    stage16(wip + (size_t)col * 32 + cx8s,
            lds + 32768 + 8192 + half * 4096 + tid * 8);
  };
  auto ldsr = [&](int byteoff) -> short8 {
    return *reinterpret_cast<const short8*>(reinterpret_cast<const char*>(lds) + byteoff);
  };

  // shared per-lane LDS read bases (k=0/k=1), immediates carry m/n/MH/NH
  const int vaA0 = (wm * 128 + lc) * 128 + ((lk * 16) ^ swz);
  const int vaA1 = (wm * 128 + lc) * 128 + ((64 + lk * 16) ^ swz);
  const int vaB0 = 32768 + (wn * 32 + lc) * 128 + ((lk * 16) ^ swz);
  const int vaB1 = 32768 + (wn * 32 + lc) * 128 + ((64 + lk * 16) ^ swz);

  floatx4 acc[8][4];
#pragma unroll
  for (int i = 0; i < 8; ++i)
#pragma unroll
    for (int j = 0; j < 4; ++j) acc[i][j] = (floatx4){0.f, 0.f, 0.f, 0.f};

  // fragment register sets (one-phase-ahead pipeline; b0 doubled for tile-parity wrap)
  short8 a0[4][2], a1[4][2], b0e[2][2], b0o[2][2], b1[2][2];

#define LOAD_A_TO(ARR, PB, MH)                                                   \
  _Pragma("unroll") for (int m_ = 0; m_ < 4; ++m_) {                             \
    ARR[m_][0] = ldsr((PB) + vaA0 + ((MH) * 64 + m_ * 16) * 128);                \
    ARR[m_][1] = ldsr((PB) + vaA1 + ((MH) * 64 + m_ * 16) * 128);                \
  }
#define LOAD_B_TO(ARR, PB, NH)                                                   \
  _Pragma("unroll") for (int n_ = 0; n_ < 2; ++n_) {                             \
    ARR[n_][0] = ldsr((PB) + vaB0 + ((NH) * 128 + n_ * 16) * 128);               \
    ARR[n_][1] = ldsr((PB) + vaB1 + ((NH) * 128 + n_ * 16) * 128);               \
  }
#define MFMA_Q(AR, BR, MH, NH)                                                   \
  __builtin_amdgcn_s_setprio(1);                                                 \
  _Pragma("unroll") for (int m_ = 0; m_ < 4; ++m_)                               \
  _Pragma("unroll") for (int n_ = 0; n_ < 2; ++n_)                               \
  _Pragma("unroll") for (int k_ = 0; k_ < 2; ++k_)                               \
    acc[(MH) * 4 + m_][(NH) * 2 + n_] = __builtin_amdgcn_mfma_f32_16x16x32_bf16( \
        AR[m_][k_], BR[n_][k_], acc[(MH) * 4 + m_][(NH) * 2 + n_], 0, 0, 0);     \
  __builtin_amdgcn_s_setprio(0);
#define PHASE_END                                                                \
  asm volatile("s_waitcnt vmcnt(8)" ::: "memory");                               \
  __builtin_amdgcn_sched_barrier(0);                                             \
  __builtin_amdgcn_s_barrier();                                                  \
  __builtin_amdgcn_sched_barrier(0);
#define HARD_SYNC(VM)                                                            \
  asm volatile("s_waitcnt vmcnt(" #VM ")" ::: "memory");                         \
  __builtin_amdgcn_sched_barrier(0);                                             \
  __builtin_amdgcn_s_barrier();                                                  \
  __builtin_amdgcn_sched_barrier(0);

  if (first) {
    // x-projection only
    stageXA(0); stageXA(1); stageXB(0); stageXB(1);
    HARD_SYNC(0)
    short8 xb4[4];
#pragma unroll
    for (int nf = 0; nf < 4; ++nf)
      xb4[nf] = ldsr(65536 + 16384 +
                     ((nf >> 1) * 128 + wn * 32 + (nf & 1) * 16 + lc) * 64 +
                     ((lk * 16) ^ swzx));
#pragma unroll
    for (int mf = 0; mf < 8; ++mf) {
      short8 xa = ldsr(65536 + (wm * 128 + mf * 16 + lc) * 64 + ((lk * 16) ^ swzx));
#pragma unroll
      for (int nf = 0; nf < 4; ++nf)
        acc[mf][nf] = __builtin_amdgcn_mfma_f32_16x16x32_bf16(xa, xb4[nf], acc[mf][nf], 0, 0, 0);
    }
  } else {
    // ---- prologue: x (buf1 overlay) + tile0 -> buf0 ----
    stageXA(0); stageXA(1); stageXB(0); stageXB(1);
#pragma unroll
    for (int j = 0; j < 4; ++j) stageB(0, 0, j);
#pragma unroll
    for (int i = 0; i < 4; ++i) stageA(0, 0, i);
    HARD_SYNC(8)                              // x landed; tile0's 8 in flight
    // ---- x compute (reads buf1 overlay) ----
    {
      short8 xb4[4];
#pragma unroll
      for (int nf = 0; nf < 4; ++nf)
        xb4[nf] = ldsr(65536 + 16384 +
                       ((nf >> 1) * 128 + wn * 32 + (nf & 1) * 16 + lc) * 64 +
                       ((lk * 16) ^ swzx));
      __builtin_amdgcn_s_setprio(1);
#pragma unroll
      for (int mf = 0; mf < 8; ++mf) {
        short8 xa = ldsr(65536 + (wm * 128 + mf * 16 + lc) * 64 + ((lk * 16) ^ swzx));
#pragma unroll
        for (int nf = 0; nf < 4; ++nf)
          acc[mf][nf] = __builtin_amdgcn_mfma_f32_16x16x32_bf16(xa, xb4[nf], acc[mf][nf], 0, 0, 0);
      }
      __builtin_amdgcn_s_setprio(0);
      asm volatile("s_waitcnt lgkmcnt(0)" ::: "memory");  // x reads drained before overlay overwrite
      __builtin_amdgcn_sched_barrier(0);
    }
    __builtin_amdgcn_s_barrier();
    __builtin_amdgcn_sched_barrier(0);
    // ---- tile1 -> buf1 (overwrites x overlay) ----
#pragma unroll
    for (int j = 0; j < 4; ++j) stageB(32768, 1, j);
#pragma unroll
    for (int i = 0; i < 4; ++i) stageA(32768, 1, i);
    HARD_SYNC(8)                              // tile0 landed; tile1's 8 in flight
    // ---- ph0: prime a0 (mh0) and b0e (nh0) from tile0 ----
    LOAD_A_TO(a0, 0, 0)
    LOAD_B_TO(b0e, 0, 0)
    asm volatile("s_waitcnt lgkmcnt(0)" ::: "memory");  // reads done before phE1's stages
    __builtin_amdgcn_sched_barrier(0);
    __builtin_amdgcn_s_barrier();
    __builtin_amdgcn_sched_barrier(0);

    // ---- main loop: 2 K-tiles (E=kt buf0, O=kt+1 buf1) per iteration, 8 phases ----
    for (int kt = 0; kt < NT_; kt += 2) {
      // phE1: MFMA(0,0)[a0,b0e]; read b1<-nh1(E); stage Bnh0(E+2)
      if (kt + 2 < NT_) { stageB(0, kt + 2, 0); stageB(0, kt + 2, 1); }
      LOAD_B_TO(b1, 0, 1)
      MFMA_Q(a0, b0e, 0, 0)
      PHASE_END
      // phE2: MFMA(0,1)[a0,b1]; read a1<-mh1(E); stage Amh0(E+2)
      if (kt + 2 < NT_) { stageA(0, kt + 2, 0); stageA(0, kt + 2, 1); }
      LOAD_A_TO(a1, 0, 1)
      MFMA_Q(a0, b1, 0, 1)
      PHASE_END
      // phE3: MFMA(1,1)[a1,b1]; read b0o<-nh0(O,buf1); stage Bnh1(E+2)
      if (kt + 2 < NT_) { stageB(0, kt + 2, 2); stageB(0, kt + 2, 3); }
      LOAD_B_TO(b0o, 65536, 0)
      MFMA_Q(a1, b1, 1, 1)
      PHASE_END
      // phE4: MFMA(1,0)[a1,b0e]; read a0<-mh0(O,buf1); stage Amh1(E+2)
      if (kt + 2 < NT_) { stageA(0, kt + 2, 2); stageA(0, kt + 2, 3); }
      LOAD_A_TO(a0, 65536, 0)
      MFMA_Q(a1, b0e, 1, 0)
      PHASE_END
      // phO1: MFMA(0,0)[a0,b0o]; read b1<-nh1(O); stage Bnh0(O+2)
      if (kt + 3 < NT_) { stageB(32768, kt + 3, 0); stageB(32768, kt + 3, 1); }
      LOAD_B_TO(b1, 65536, 1)
      MFMA_Q(a0, b0o, 0, 0)
      PHASE_END
      // phO2: MFMA(0,1)[a0,b1]; read a1<-mh1(O); stage Amh0(O+2)
      if (kt + 3 < NT_) { stageA(32768, kt + 3, 0); stageA(32768, kt + 3, 1); }
      LOAD_A_TO(a1, 65536, 1)
      MFMA_Q(a0, b1, 0, 1)
      PHASE_END
      // phO3: MFMA(1,1)[a1,b1]; read b0e<-nh0(E+2,buf0); stage Bnh1(O+2)
      if (kt + 3 < NT_) { stageB(32768, kt + 3, 2); stageB(32768, kt + 3, 3); }
      LOAD_B_TO(b0e, 0, 0)
      MFMA_Q(a1, b1, 1, 1)
      PHASE_END
      // phO4: MFMA(1,0)[a1,b0o]; read a0<-mh0(E+2,buf0); stage Amh1(O+2)
      if (kt + 3 < NT_) { stageA(32768, kt + 3, 2); stageA(32768, kt + 3, 3); }
      LOAD_A_TO(a0, 0, 0)
      MFMA_Q(a1, b0o, 1, 0)
      PHASE_END
    }
  }

  // ---- epilogue: frag n == gate; fused LSTM cell update ----
  const int jj  = (by * 4 + wn) * 16 + lc;       // h column 0..1023
  const float bi  = bias[jj];
  const float bf_ = bias[H_ + jj];
  const float bg_ = bias[2 * H_ + jj];
  const float bo_ = bias[3 * H_ + jj];
#pragma unroll
  for (int mf = 0; mf < 8; ++mf) {
    const int rbase = m0 + wm * 128 + mf * 16 + lk * 4;
#pragma unroll
    for (int r = 0; r < 4; ++r) {
      const size_t idx = (size_t)(rbase + r) * H_ + jj;
      float ig = sigm(acc[mf][0][r] + bi);
      float fg = sigm(acc[mf][1][r] + bf_);
      float gg = tanh_f(acc[mf][2][r] + bg_);
      float og = sigm(acc[mf][3][r] + bo_);
      float cp = first ? 0.f : cst[idx];
      float cn = fg * cp + ig * gg;
      cst[idx] = cn;
      hnext[idx] = f2bf(og * tanh_f(cn));
    }
  }
#undef LOAD_A_TO
#undef LOAD_B_TO
#undef MFMA_Q
#undef PHASE_END
#undef HARD_SYNC
}

// ---------- classifier: out = h @ Wc + bc ----------
__global__ __launch_bounds__(256) void cls_kernel(const unsigned short* __restrict__ h,
                                                  const float* __restrict__ wc,
                                                  const float* __restrict__ bc,
                                                  float* __restrict__ out) {
  int w = threadIdx.x >> 6, l = threadIdx.x & 63;
  int row = blockIdx.x * 4 + w;
  float acc[OUT_];
#pragma unroll
  for (int o = 0; o < OUT_; ++o) acc[o] = 0.f;
  const unsigned short* hr = h + row * H_;
  for (int k = l; k < H_; k += 64) {
    float hv = bf2f(hr[k]);
#pragma unroll
    for (int o = 0; o < OUT_; ++o) acc[o] += hv * wc[k * OUT_ + o];
  }
#pragma unroll
  for (int o = 0; o < OUT_; ++o) {
    float v = acc[o];
#pragma unroll
    for (int s = 32; s > 0; s >>= 1) v += __shfl_down(v, s, 64);
    if (l == 0) out[row * OUT_ + o] = v + bc[o];
  }
}

extern "C" void kernel_launch(void* const* d_in, const int* in_sizes, int n_in,
                              void* d_out, int out_size, void* d_ws, size_t ws_size,
                              hipStream_t stream) {
  const float* x    = (const float*)d_in[0];
  const float* wih  = (const float*)d_in[1];
  const float* whh  = (const float*)d_in[2];
  const float* bias = (const float*)d_in[3];
  const float* wc   = (const float*)d_in[4];
  const float* bc   = (const float*)d_in[5];
  float* out = (float*)d_out;

  char* ws = (char*)d_ws;
  unsigned short* wp  = (unsigned short*)(ws);                 //  8 MB  permuted W_hh^T bf16
  unsigned short* wip = (unsigned short*)(ws + 8388608);       //  256KB permuted W_ih^T bf16
  unsigned short* xb  = (unsigned short*)(ws + 8650752);       //  7 MB  x bf16 [T][B][32]
  unsigned short* h0  = (unsigned short*)(ws + 15990784);      //  8 MB
  unsigned short* h1  = (unsigned short*)(ws + 24379392);      //  8 MB
  float*          cst = (float*)(ws + 32768000);               // 16 MB fp32 cell state

  hipLaunchKernelGGL(conv_x_kernel,  dim3(448), dim3(256), 0, stream, x, xb);
  hipLaunchKernelGGL(perm_whh_kernel, dim3(256), dim3(256), 0, stream, whh, wp);
  hipLaunchKernelGGL(perm_wih_kernel, dim3(256), dim3(256), 0, stream, wih, wip);

  unsigned short* hb[2] = {h0, h1};
  for (int t = 0; t < T_; ++t) {
    unsigned short* hn = hb[t & 1];
    unsigned short* hp = hb[(t & 1) ^ 1];
    hipLaunchKernelGGL(lstm_step_kernel, dim3(256), dim3(512), 0, stream,
                       hp, wp, xb + (size_t)t * (B_ * 32), wip, bias, cst, hn,
                       (t == 0) ? 1 : 0);
  }
  hipLaunchKernelGGL(cls_kernel, dim3(1024), dim3(256), 0, stream, hb[1], wc, bc, out);
}

// Round 5
// 1118.961 us; speedup vs baseline: 1.5093x; 1.5093x over previous
//
#include <hip/hip_runtime.h>
#include <stdint.h>

#define GLOBAL_AS __attribute__((address_space(1)))
#define LDS_AS    __attribute__((address_space(3)))

typedef __attribute__((ext_vector_type(8))) short  short8;   // 8 bf16 = 4 VGPRs
typedef __attribute__((ext_vector_type(4))) float  floatx4;

static constexpr int B_   = 4096;
static constexpr int T_   = 28;
static constexpr int IN_  = 28;
static constexpr int H_   = 1024;
static constexpr int G4_  = 4096;   // 4*H
static constexpr int OUT_ = 10;
static constexpr int NT_  = 16;     // K-tiles of 64 over H=1024

// ---------- small helpers ----------
__device__ __forceinline__ float bf2f(unsigned short u) {
  union { uint32_t i; float f; } v; v.i = ((uint32_t)u) << 16; return v.f;
}
__device__ __forceinline__ unsigned short f2bf(float f) {  // RTNE
  union { float f; uint32_t i; } v; v.f = f;
  uint32_t x = v.i;
  uint32_t lsb = (x >> 16) & 1u;
  x += 0x7fffu + lsb;
  return (unsigned short)(x >> 16);
}
__device__ __forceinline__ float sigm(float x) {
  return __builtin_amdgcn_rcpf(1.f + __builtin_amdgcn_exp2f(-1.4426950408889634f * x));
}
__device__ __forceinline__ float tanh_f(float x) {
  return 1.f - 2.f * __builtin_amdgcn_rcpf(1.f + __builtin_amdgcn_exp2f(2.8853900817779268f * x));
}
__device__ __forceinline__ void stage16(const unsigned short* g, unsigned short* l) {
  __builtin_amdgcn_global_load_lds(
      (const GLOBAL_AS uint32_t*)g, (LDS_AS uint32_t*)l, 16, 0, 0);
}

// ---------- prologue: x -> bf16 [T][B][32] (k padded 28->32 with zeros) ----------
__global__ __launch_bounds__(256) void conv_x_kernel(const float* __restrict__ x,
                                                     unsigned short* __restrict__ xb) {
  int row = blockIdx.x * 256 + threadIdx.x;   // row = t*4096 + b
  int t  = row >> 12;
  int bb = row & 4095;
  const float* src = x + (bb * T_ + t) * IN_;
  unsigned short* dst = xb + row * 32;
#pragma unroll
  for (int k = 0; k < IN_; ++k) dst[k] = f2bf(src[k]);
  dst[28] = 0; dst[29] = 0; dst[30] = 0; dst[31] = 0;
}

// ---------- prologue: W_hh [1024][4096] fp32 -> Wp [4096][1024] bf16, transposed+interleaved ----------
// permuted n = g64*64 + gate*16 + hw  <->  orig col = gate*1024 + g64*16 + hw
__global__ __launch_bounds__(256) void perm_whh_kernel(const float* __restrict__ whh,
                                                       unsigned short* __restrict__ wp) {
  __shared__ float lds[64][17];
  int g64  = blockIdx.x >> 2;
  int gate = blockIdx.x & 3;
  int oc0  = gate * H_ + g64 * 16;
  int n0   = g64 * 64 + gate * 16;
  int tid  = threadIdx.x;
  for (int kc = 0; kc < 16; ++kc) {
    int k0 = kc * 64;
    __syncthreads();
#pragma unroll
    for (int e = 0; e < 4; ++e) {
      int idx = e * 256 + tid;
      int k = idx >> 4, cc = idx & 15;
      lds[k][cc] = whh[(k0 + k) * G4_ + oc0 + cc];
    }
    __syncthreads();
#pragma unroll
    for (int e = 0; e < 4; ++e) {
      int idx = e * 256 + tid;
      int n = idx >> 6, kk = idx & 63;
      wp[(n0 + n) * H_ + k0 + kk] = f2bf(lds[kk][n]);
    }
  }
}

// ---------- prologue: W_ih [28][4096] -> Wip [4096][32] bf16 transposed+interleaved ----------
__global__ __launch_bounds__(256) void perm_wih_kernel(const float* __restrict__ wih,
                                                       unsigned short* __restrict__ wip) {
  __shared__ float lds[28][17];
  int g64  = blockIdx.x >> 2;
  int gate = blockIdx.x & 3;
  int oc0  = gate * H_ + g64 * 16;
  int n0   = g64 * 64 + gate * 16;
  int tid  = threadIdx.x;
  for (int idx = tid; idx < 448; idx += 256) {
    int k = idx >> 4, cc = idx & 15;
    lds[k][cc] = wih[k * G4_ + oc0 + cc];
  }
  __syncthreads();
#pragma unroll
  for (int e = 0; e < 2; ++e) {
    int idx = e * 256 + tid;
    int n = idx >> 5, kk = idx & 31;
    wip[(n0 + n) * 32 + kk] = (kk < IN_) ? f2bf(lds[kk][n]) : (unsigned short)0;
  }
}

// ================== LSTM step: 256x256 tile, 4-phase/K-tile, single barrier per phase ==================
// 8 waves (2M x 4N), per-wave 128x64, BK=64. In-phase fragment consumption with COMPILER-COUNTED
// lgkmcnt waits (no forced full drains); one s_barrier per phase (sched_barrier(0)-fenced);
// counted vmcnt(6) once per K-tile (never 0 mid-loop). T2 swizzle via pre-swizzled global source.
__global__ __launch_bounds__(512, 2) void lstm_step_kernel(
    const unsigned short* __restrict__ hprev,   // [B][H] bf16
    const unsigned short* __restrict__ wp,      // [4096][1024] bf16 (permuted^T)
    const unsigned short* __restrict__ xbt,     // [B][32] bf16 (this t)
    const unsigned short* __restrict__ wip,     // [4096][32] bf16 (permuted^T)
    const float* __restrict__ bias,             // [4096] original gate order
    float* __restrict__ cst,                    // [B][H] fp32
    unsigned short* __restrict__ hnext,         // [B][H] bf16
    int first) {
  __shared__ __align__(16) unsigned short lds[65536];   // 128 KiB: 2 x (A 32KB | B 32KB)

  const int tid = threadIdx.x;           // 0..511
  const int w   = tid >> 6;              // wave 0..7
  const int l   = tid & 63;
  const int wm  = w >> 2;                // 0..1  (M half)
  const int wn  = w & 3;                 // 0..3  (N quarter)
  const int lc  = l & 15;
  const int lk  = l >> 4;                // 0..3

  // XCD-aware bijective block swizzle (256 = 8*32)
  const int hid = blockIdx.x;
  const int lid = (hid & 7) * 32 + (hid >> 3);
  const int bx  = lid & 15, by = lid >> 4;
  const int m0  = bx * 256;              // batch rows
  const int n0  = by * 256;              // permuted gate cols

  const int swz  = (lc & 7) << 4;        // ds_read byte swizzle (main, 128B rows)
  const int swzx = (lc & 3) << 4;        // x-tile (64B rows)

  // ---- staging per-thread constants ----
  const int r8  = tid >> 3;              // main chunk-local row 0..63
  const int c8  = (tid & 7) * 8;         // ushort col within 64
  const int c8s = c8 ^ ((r8 & 7) * 8);   // pre-swizzled source col
  const size_t aoff = (size_t)(m0 + r8) * H_ + c8s;
  const int bwn_low = r8 >> 5;
  const int bc31    = r8 & 31;
  const int rx   = tid >> 2;             // x chunk-local row 0..127
  const int cx8  = (tid & 3) * 8;
  const int cx8s = cx8 ^ ((rx & 3) * 8);

  auto stageA = [&](int bufu, int kt, int i) {
    stage16(hprev + aoff + (size_t)i * (64 * H_) + kt * 64,
            lds + bufu + i * 4096 + tid * 8);
  };
  auto stageB = [&](int bufu, int kt, int j) {
    int col = n0 + (((j & 1) * 2 + bwn_low) * 64) + ((j >> 1) * 32) + bc31;
    stage16(wp + (size_t)col * H_ + c8s + kt * 64,
            lds + bufu + 16384 + j * 4096 + tid * 8);
  };
  auto stageXA = [&](int half) {
    int row = half * 128 + rx;
    stage16(xbt + (size_t)(m0 + row) * 32 + cx8s,
            lds + 32768 + half * 4096 + tid * 8);
  };
  auto stageXB = [&](int half) {
    int col = n0 + (rx >> 5) * 64 + half * 32 + (rx & 31);
    stage16(wip + (size_t)col * 32 + cx8s,
            lds + 32768 + 8192 + half * 4096 + tid * 8);
  };
  auto ldsr = [&](int byteoff) -> short8 {
    return *reinterpret_cast<const short8*>(reinterpret_cast<const char*>(lds) + byteoff);
  };

  floatx4 acc[8][4];
#pragma unroll
  for (int i = 0; i < 8; ++i)
#pragma unroll
    for (int j = 0; j < 4; ++j) acc[i][j] = (floatx4){0.f, 0.f, 0.f, 0.f};

  short8 a[4][2], b[2][2];

#define LOAD_A(PB, MH)                                                               \
  _Pragma("unroll") for (int m_ = 0; m_ < 4; ++m_)                                   \
  _Pragma("unroll") for (int k_ = 0; k_ < 2; ++k_)                                   \
    a[m_][k_] = ldsr((PB) + (wm * 128 + (MH) * 64 + m_ * 16 + lc) * 128 +            \
                     ((k_ * 64 + lk * 16) ^ swz));

#define LOAD_B(PB, NH)                                                               \
  _Pragma("unroll") for (int n_ = 0; n_ < 2; ++n_)                                   \
  _Pragma("unroll") for (int k_ = 0; k_ < 2; ++k_)                                   \
    b[n_][k_] = ldsr((PB) + 32768 + ((NH) * 128 + wn * 32 + n_ * 16 + lc) * 128 +    \
                     ((k_ * 64 + lk * 16) ^ swz));

// MFMA cluster: no explicit waits -- compiler emits counted lgkmcnt per consuming MFMA.
#define MFMA_Q(MH, NH)                                                               \
  __builtin_amdgcn_s_setprio(1);                                                     \
  _Pragma("unroll") for (int m_ = 0; m_ < 4; ++m_)                                   \
  _Pragma("unroll") for (int n_ = 0; n_ < 2; ++n_)                                   \
  _Pragma("unroll") for (int k_ = 0; k_ < 2; ++k_)                                   \
    acc[(MH) * 4 + m_][(NH) * 2 + n_] = __builtin_amdgcn_mfma_f32_16x16x32_bf16(     \
        a[m_][k_], b[n_][k_], acc[(MH) * 4 + m_][(NH) * 2 + n_], 0, 0, 0);           \
  __builtin_amdgcn_s_setprio(0);

// Single barrier per phase; sched_barrier(0) on both sides pins all phase-p ops
// (incl. MFMAs + their counted waits) before the barrier -- staging-overwrite safety.
#define PH_BAR                                                                       \
  __builtin_amdgcn_sched_barrier(0);                                                 \
  __builtin_amdgcn_s_barrier();                                                      \
  __builtin_amdgcn_sched_barrier(0);

#define TILE_BAR(VM)                                                                 \
  __builtin_amdgcn_sched_barrier(0);                                                 \
  asm volatile("s_waitcnt vmcnt(" #VM ")" ::: "memory");                             \
  __builtin_amdgcn_s_barrier();                                                      \
  __builtin_amdgcn_sched_barrier(0);

  if (first) {
    // x-projection only
    stageXA(0); stageXA(1); stageXB(0); stageXB(1);
    TILE_BAR(0)
    short8 xb4[4];
#pragma unroll
    for (int nf = 0; nf < 4; ++nf)
      xb4[nf] = ldsr(65536 + 16384 +
                     ((nf >> 1) * 128 + wn * 32 + (nf & 1) * 16 + lc) * 64 +
                     ((lk * 16) ^ swzx));
#pragma unroll
    for (int mf = 0; mf < 8; ++mf) {
      short8 xa = ldsr(65536 + (wm * 128 + mf * 16 + lc) * 64 + ((lk * 16) ^ swzx));
#pragma unroll
      for (int nf = 0; nf < 4; ++nf)
        acc[mf][nf] = __builtin_amdgcn_mfma_f32_16x16x32_bf16(xa, xb4[nf], acc[mf][nf], 0, 0, 0);
    }
  } else {
    // ---- prologue: x (buf1 overlay) + tile0 -> buf0 ----
    stageXA(0); stageXA(1); stageXB(0); stageXB(1);
#pragma unroll
    for (int j = 0; j < 4; ++j) stageB(0, 0, j);
#pragma unroll
    for (int i = 0; i < 4; ++i) stageA(0, 0, i);
    TILE_BAR(8)                               // x landed; tile0's 8 in flight
    // ---- x compute (reads buf1 overlay; consumption pins read completion) ----
    {
      short8 xb4[4];
#pragma unroll
      for (int nf = 0; nf < 4; ++nf)
        xb4[nf] = ldsr(65536 + 16384 +
                       ((nf >> 1) * 128 + wn * 32 + (nf & 1) * 16 + lc) * 64 +
                       ((lk * 16) ^ swzx));
      __builtin_amdgcn_s_setprio(1);
#pragma unroll
      for (int mf = 0; mf < 8; ++mf) {
        short8 xa = ldsr(65536 + (wm * 128 + mf * 16 + lc) * 64 + ((lk * 16) ^ swzx));
#pragma unroll
        for (int nf = 0; nf < 4; ++nf)
          acc[mf][nf] = __builtin_amdgcn_mfma_f32_16x16x32_bf16(xa, xb4[nf], acc[mf][nf], 0, 0, 0);
      }
      __builtin_amdgcn_s_setprio(0);
    }
    PH_BAR                                    // buf1 free for tile1 staging
    // ---- tile1 -> buf1 (overwrites x overlay) ----
#pragma unroll
    for (int j = 0; j < 4; ++j) stageB(32768, 1, j);
#pragma unroll
    for (int i = 0; i < 4; ++i) stageA(32768, 1, i);
    TILE_BAR(8)                               // tile0 landed; tile1's 8 in flight

    // ---- main loop: 16 K-tiles, 4 phases each, ONE barrier per phase ----
    for (int kt = 0; kt < NT_; ++kt) {
      const int pbB = (kt & 1) * 65536;          // current buffer, bytes
      const int pbu = (kt & 1) * 32768;          // current buffer, ushorts
      const int qbu = ((kt + 1) & 1) * 32768;    // other buffer, ushorts

      // ph1: (mh0, nh0); B first so first MFMA's operands land early
      LOAD_B(pbB, 0)
      LOAD_A(pbB, 0)
      if (kt + 1 < NT_) { stageB(qbu, kt + 1, 0); stageB(qbu, kt + 1, 1); }
      MFMA_Q(0, 0)
      PH_BAR

      // ph2: (mh0, nh1); a reused from regs
      LOAD_B(pbB, 1)
      if (kt + 2 < NT_) { stageA(pbu, kt + 2, 0); stageA(pbu, kt + 2, 2); }
      MFMA_Q(0, 1)
      PH_BAR

      // ph3: (mh1, nh1); b reused from regs
      LOAD_A(pbB, 1)
      if (kt + 2 < NT_) { stageB(pbu, kt + 2, 2); stageB(pbu, kt + 2, 3); }
      MFMA_Q(1, 1)
      PH_BAR

      // ph4: (mh1, nh0); re-read B(nh0); counted vmcnt at tile end (never 0 mid-loop)
      LOAD_B(pbB, 0)
      if (kt + 2 < NT_) { stageA(pbu, kt + 2, 1); stageA(pbu, kt + 2, 3); }
      MFMA_Q(1, 0)
      if (kt == NT_ - 2) { TILE_BAR(0) }
      else               { TILE_BAR(6) }
    }
  }

  // ---- epilogue: frag n == gate; fused LSTM cell update ----
  const int jj  = (by * 4 + wn) * 16 + lc;       // h column 0..1023
  const float bi  = bias[jj];
  const float bf_ = bias[H_ + jj];
  const float bg_ = bias[2 * H_ + jj];
  const float bo_ = bias[3 * H_ + jj];
#pragma unroll
  for (int mf = 0; mf < 8; ++mf) {
    const int rbase = m0 + wm * 128 + mf * 16 + lk * 4;
#pragma unroll
    for (int r = 0; r < 4; ++r) {
      const size_t idx = (size_t)(rbase + r) * H_ + jj;
      float ig = sigm(acc[mf][0][r] + bi);
      float fg = sigm(acc[mf][1][r] + bf_);
      float gg = tanh_f(acc[mf][2][r] + bg_);
      float og = sigm(acc[mf][3][r] + bo_);
      float cp = first ? 0.f : cst[idx];
      float cn = fg * cp + ig * gg;
      cst[idx] = cn;
      hnext[idx] = f2bf(og * tanh_f(cn));
    }
  }
#undef LOAD_A
#undef LOAD_B
#undef MFMA_Q
#undef PH_BAR
#undef TILE_BAR
}

// ---------- classifier: out = h @ Wc + bc ----------
__global__ __launch_bounds__(256) void cls_kernel(const unsigned short* __restrict__ h,
                                                  const float* __restrict__ wc,
                                                  const float* __restrict__ bc,
                                                  float* __restrict__ out) {
  int w = threadIdx.x >> 6, l = threadIdx.x & 63;
  int row = blockIdx.x * 4 + w;
  float acc[OUT_];
#pragma unroll
  for (int o = 0; o < OUT_; ++o) acc[o] = 0.f;
  const unsigned short* hr = h + row * H_;
  for (int k = l; k < H_; k += 64) {
    float hv = bf2f(hr[k]);
#pragma unroll
    for (int o = 0; o < OUT_; ++o) acc[o] += hv * wc[k * OUT_ + o];
  }
#pragma unroll
  for (int o = 0; o < OUT_; ++o) {
    float v = acc[o];
#pragma unroll
    for (int s = 32; s > 0; s >>= 1) v += __shfl_down(v, s, 64);
    if (l == 0) out[row * OUT_ + o] = v + bc[o];
  }
}

extern "C" void kernel_launch(void* const* d_in, const int* in_sizes, int n_in,
                              void* d_out, int out_size, void* d_ws, size_t ws_size,
                              hipStream_t stream) {
  const float* x    = (const float*)d_in[0];
  const float* wih  = (const float*)d_in[1];
  const float* whh  = (const float*)d_in[2];
  const float* bias = (const float*)d_in[3];
  const float* wc   = (const float*)d_in[4];
  const float* bc   = (const float*)d_in[5];
  float* out = (float*)d_out;

  char* ws = (char*)d_ws;
  unsigned short* wp  = (unsigned short*)(ws);                 //  8 MB  permuted W_hh^T bf16
  unsigned short* wip = (unsigned short*)(ws + 8388608);       //  256KB permuted W_ih^T bf16
  unsigned short* xb  = (unsigned short*)(ws + 8650752);       //  7 MB  x bf16 [T][B][32]
  unsigned short* h0  = (unsigned short*)(ws + 15990784);      //  8 MB
  unsigned short* h1  = (unsigned short*)(ws + 24379392);      //  8 MB
  float*          cst = (float*)(ws + 32768000);               // 16 MB fp32 cell state

  hipLaunchKernelGGL(conv_x_kernel,  dim3(448), dim3(256), 0, stream, x, xb);
  hipLaunchKernelGGL(perm_whh_kernel, dim3(256), dim3(256), 0, stream, whh, wp);
  hipLaunchKernelGGL(perm_wih_kernel, dim3(256), dim3(256), 0, stream, wih, wip);

  unsigned short* hb[2] = {h0, h1};
  for (int t = 0; t < T_; ++t) {
    unsigned short* hn = hb[t & 1];
    unsigned short* hp = hb[(t & 1) ^ 1];
    hipLaunchKernelGGL(lstm_step_kernel, dim3(256), dim3(512), 0, stream,
                       hp, wp, xb + (size_t)t * (B_ * 32), wip, bias, cst, hn,
                       (t == 0) ? 1 : 0);
  }
  hipLaunchKernelGGL(cls_kernel, dim3(1024), dim3(256), 0, stream, hb[1], wc, bc, out);
}